// Round 1
// baseline (3189.077 us; speedup 1.0000x reference)
//
#include <hip/hip_runtime.h>
#include <hip/hip_fp16.h>
#include <math.h>

// SO2_Attention — all-f32 problem (reference is jnp.float32 end to end).
// Pipeline: node e3nn linear (center+neigh) -> per-edge gather + Wigner rotate
// + channel product (sim 240) -> 3x latent GEMM (->384) + silu -> 384x256 GEMM
// + silu -> 256x128 GEMM -> out.
//
// Round 4: barrier-free wave-private restructure.
//  - All LDS is wave-private ([w][e][...]) => removed ALL __syncthreads().
//  - Fused latent-GEMM + Wf1-GEMM per 128-chunk: latS 384 -> 132 floats/edge.
//    LDS 61.9KB -> 36.75KB => 4 blocks/CU (16 waves/CU), __launch_bounds__(256,4).
//  - Phase 2 now 2 cols/lane (float2 weights): sim LDS reads halved.

#define NFEAT 240
#define EW 6            // edges per wave
#define WPB 4           // waves per block
#define EB (EW * WPB)   // 24 edges per block
#define BUFW 260        // sim(240)/h(256) union row, padded (1040B, 16B mult)
#define LATW 132        // one 128-wide latent chunk, padded (528B, 16B mult)

__device__ __forceinline__ float silu_f(float x) {
    return x / (1.0f + __expf(-x));
}

// ---------------- Kernel A: per-node e3nn linear (center + neigh) -------------
template <bool F32>
__global__ void node_kernel(const float* __restrict__ x,
                            const float* __restrict__ Wc0, const float* __restrict__ bc0,
                            const float* __restrict__ Wc1, const float* __restrict__ Wc2,
                            const float* __restrict__ Wn0, const float* __restrict__ bn0,
                            const float* __restrict__ Wn1, const float* __restrict__ Wn2,
                            void* __restrict__ Cp, void* __restrict__ Np,
                            int n_nodes)
{
    int t = blockIdx.x * blockDim.x + threadIdx.x;
    int total = n_nodes * NFEAT;
    if (t >= total) return;
    int n = t / NFEAT;
    int j = t - n * NFEAT;
    const float* xr = x + (size_t)n * NFEAT;
    float ac = 0.f, an = 0.f;
    if (j < 64) {
        #pragma unroll 8
        for (int m = 0; m < 64; ++m) {
            float xv = xr[m];
            ac = fmaf(xv, Wc0[m * 64 + j], ac);
            an = fmaf(xv, Wn0[m * 64 + j], an);
        }
        ac = ac * 0.125f + bc0[j];
        an = an * 0.125f + bn0[j];
    } else if (j < 160) {
        int s = j - 64; int k = s / 3; int d = s - 3 * k;
        #pragma unroll 8
        for (int m = 0; m < 32; ++m) {
            float xv = xr[64 + m * 3 + d];
            ac = fmaf(xv, Wc1[m * 32 + k], ac);
            an = fmaf(xv, Wn1[m * 32 + k], an);
        }
        const float s32 = 0.17677669529663687f; // 1/sqrt(32)
        ac *= s32; an *= s32;
    } else {
        int s = j - 160; int k = s / 5; int d = s - 5 * k;
        #pragma unroll 8
        for (int m = 0; m < 16; ++m) {
            float xv = xr[160 + m * 5 + d];
            ac = fmaf(xv, Wc2[m * 16 + k], ac);
            an = fmaf(xv, Wn2[m * 16 + k], an);
        }
        ac *= 0.25f; an *= 0.25f;
    }
    if (F32) {
        ((float*)Cp)[t] = ac;
        ((float*)Np)[t] = an;
    } else {
        ((__half*)Cp)[t] = __float2half(ac);
        ((__half*)Np)[t] = __float2half(an);
    }
}

// ---------------- Kernel B: fused per-edge pipeline ---------------------------
// 256 threads = 4 waves; each wave owns EW=6 consecutive edges.
// All LDS is wave-private: DS ops within a wave complete in order, so no
// __syncthreads() anywhere; wave_barrier() pseudos (zero-cost) pin compiler
// ordering at phase boundaries.
template <bool F32>
__global__ __launch_bounds__(256, 4) void edge_kernel(
    const void* __restrict__ Cp, const void* __restrict__ Np,
    const int* __restrict__ eidx, const float* __restrict__ wig,
    const float* __restrict__ Ws0, const float* __restrict__ bs0,
    const float* __restrict__ Ws1, const float* __restrict__ bs1,
    const float* __restrict__ Ws2, const float* __restrict__ bs2,
    const float* __restrict__ Wf1, const float* __restrict__ bf1,
    const float* __restrict__ Wf2, const float* __restrict__ bf2v,
    float* __restrict__ out, int n_edges)
{
    __shared__ __align__(16) float bufS[WPB][EW][BUFW]; // sim(240) then h(256): 24.4 KB
    __shared__ __align__(16) float latS[WPB][EW][LATW]; // one 128-chunk of lat: 12.4 KB

    const int w = threadIdx.x >> 6;
    const int lane = threadIdx.x & 63;
    const long e0 = (long)blockIdx.x * EB + (long)w * EW;

    const float* Crow[EW];
    const float* Nrow[EW];
    const __half* Chrow[EW];
    const __half* Nhrow[EW];
    bool act[EW];
    #pragma unroll
    for (int e = 0; e < EW; ++e) {
        long eg = e0 + e;
        act[e] = eg < n_edges;
        long i0 = 0, i1 = 0;
        if (act[e]) { i0 = eidx[eg]; i1 = eidx[(long)n_edges + eg]; }
        if (F32) {
            Crow[e] = (const float*)Cp + i0 * NFEAT;
            Nrow[e] = (const float*)Np + i1 * NFEAT;
        } else {
            Chrow[e] = (const __half*)Cp + i0 * NFEAT;
            Nhrow[e] = (const __half*)Np + i1 * NFEAT;
        }
    }
    #define LDC(e, i) (F32 ? Crow[e][i] : __half2float(Chrow[e][i]))
    #define LDN(e, i) (F32 ? Nrow[e][i] : __half2float(Nhrow[e][i]))

    // ---- Phase 1: sim[e][0..240) into bufS (wave-private) ----
    #pragma unroll
    for (int e = 0; e < EW; ++e) {
        if (act[e]) {
            float c = LDC(e, lane);
            float n = LDN(e, lane);
            bufS[w][e][lane] = c * n;
        }
    }
    // l=1: tasks 6*32=192 -> 3 iters; e = t/32, m = t%32
    #pragma unroll
    for (int it = 0; it < 3; ++it) {
        int t = it * 64 + lane;
        int e = t >> 5;
        int m = t & 31;
        if (act[e]) {
            long eg = e0 + e;
            const float* wg = wig + eg * 81;
            int base = 64 + m * 3;
            float c0 = LDC(e, base + 0), c1 = LDC(e, base + 1), c2 = LDC(e, base + 2);
            float n0 = LDN(e, base + 0), n1 = LDN(e, base + 1), n2 = LDN(e, base + 2);
            #pragma unroll
            for (int q = 0; q < 3; ++q) {
                float r0 = wg[(1 + 0) * 9 + (1 + q)];
                float r1 = wg[(1 + 1) * 9 + (1 + q)];
                float r2 = wg[(1 + 2) * 9 + (1 + q)];
                float cq = c0 * r0 + c1 * r1 + c2 * r2;
                float nq = n0 * r0 + n1 * r1 + n2 * r2;
                bufS[w][e][base + q] = cq * nq;
            }
        }
    }
    // l=2: tasks 6*16=96 -> iter0: 64 lanes, iter1: 32 lanes
    #pragma unroll
    for (int it = 0; it < 2; ++it) {
        int t = it * 64 + lane;
        if (t < 96) {
            int e = t >> 4;
            int m = t & 15;
            if (act[e]) {
                long eg = e0 + e;
                const float* wg = wig + eg * 81;
                int base = 160 + m * 5;
                float c[5], n[5];
                #pragma unroll
                for (int d = 0; d < 5; ++d) { c[d] = LDC(e, base + d); n[d] = LDN(e, base + d); }
                #pragma unroll
                for (int q = 0; q < 5; ++q) {
                    float cq = 0.f, nq = 0.f;
                    #pragma unroll
                    for (int d = 0; d < 5; ++d) {
                        float rv = wg[(4 + d) * 9 + (4 + q)];
                        cq = fmaf(c[d], rv, cq);
                        nq = fmaf(n[d], rv, nq);
                    }
                    bufS[w][e][base + q] = cq * nq;
                }
            }
        }
    }
    __builtin_amdgcn_wave_barrier();

    // ---- Phases 2+3 fused: per 128-chunk l, lat -> latS, then accumulate Wf1 ----
    // Persistent Wf1 accumulators: lane owns output cols k0..k0+3 for all 6 edges.
    const int k0 = lane * 4;
    float4 hacc[EW];
    {
        float4 hb = *(const float4*)&bf1[k0];
        #pragma unroll
        for (int e = 0; e < EW; ++e) hacc[e] = hb;
    }

    {
        const float* Wsl[3] = { Ws0, Ws1, Ws2 };
        const float* bsl[3] = { bs0, bs1, bs2 };
        const int Kl[3] = { 64, 96, 80 };
        const int offl[3] = { 0, 64, 160 };
        #pragma unroll
        for (int l = 0; l < 3; ++l) {
            // -- GEMM1 chunk: 128 lat cols, 2 consecutive per lane --
            const float* W = Wsl[l];
            const int K = Kl[l];
            const int off = offl[l];
            const int c0 = lane * 2;
            float acc0[EW], acc1[EW];
            {
                float b0v = bsl[l][c0];
                float b1v = bsl[l][c0 + 1];
                #pragma unroll
                for (int e = 0; e < EW; ++e) { acc0[e] = b0v; acc1[e] = b1v; }
            }
            for (int i0 = 0; i0 < K; i0 += 4) {
                float2 w0 = *(const float2*)&W[(i0 + 0) * 128 + c0];
                float2 w1 = *(const float2*)&W[(i0 + 1) * 128 + c0];
                float2 w2 = *(const float2*)&W[(i0 + 2) * 128 + c0];
                float2 w3 = *(const float2*)&W[(i0 + 3) * 128 + c0];
                #pragma unroll
                for (int e = 0; e < EW; ++e) {
                    float4 sv = *(const float4*)&bufS[w][e][off + i0];
                    acc0[e] = fmaf(sv.x, w0.x, acc0[e]);
                    acc0[e] = fmaf(sv.y, w1.x, acc0[e]);
                    acc0[e] = fmaf(sv.z, w2.x, acc0[e]);
                    acc0[e] = fmaf(sv.w, w3.x, acc0[e]);
                    acc1[e] = fmaf(sv.x, w0.y, acc1[e]);
                    acc1[e] = fmaf(sv.y, w1.y, acc1[e]);
                    acc1[e] = fmaf(sv.z, w2.y, acc1[e]);
                    acc1[e] = fmaf(sv.w, w3.y, acc1[e]);
                }
            }
            #pragma unroll
            for (int e = 0; e < EW; ++e) {
                float2 lv;
                lv.x = silu_f(acc0[e]);
                lv.y = silu_f(acc1[e]);
                *(float2*)&latS[w][e][c0] = lv;
            }
            __builtin_amdgcn_wave_barrier();

            // -- GEMM2 partial: this chunk's 128 k rows of Wf1 --
            const float* W1 = Wf1 + (size_t)l * 128 * 256;
            for (int i0 = 0; i0 < 128; i0 += 4) {
                float4 w0 = *(const float4*)&W1[(size_t)(i0 + 0) * 256 + k0];
                float4 w1 = *(const float4*)&W1[(size_t)(i0 + 1) * 256 + k0];
                float4 w2 = *(const float4*)&W1[(size_t)(i0 + 2) * 256 + k0];
                float4 w3 = *(const float4*)&W1[(size_t)(i0 + 3) * 256 + k0];
                #pragma unroll
                for (int e = 0; e < EW; ++e) {
                    float4 lv = *(const float4*)&latS[w][e][i0];
                    hacc[e].x = fmaf(lv.x, w0.x, hacc[e].x); hacc[e].x = fmaf(lv.y, w1.x, hacc[e].x);
                    hacc[e].x = fmaf(lv.z, w2.x, hacc[e].x); hacc[e].x = fmaf(lv.w, w3.x, hacc[e].x);
                    hacc[e].y = fmaf(lv.x, w0.y, hacc[e].y); hacc[e].y = fmaf(lv.y, w1.y, hacc[e].y);
                    hacc[e].y = fmaf(lv.z, w2.y, hacc[e].y); hacc[e].y = fmaf(lv.w, w3.y, hacc[e].y);
                    hacc[e].z = fmaf(lv.x, w0.z, hacc[e].z); hacc[e].z = fmaf(lv.y, w1.z, hacc[e].z);
                    hacc[e].z = fmaf(lv.z, w2.z, hacc[e].z); hacc[e].z = fmaf(lv.w, w3.z, hacc[e].z);
                    hacc[e].w = fmaf(lv.x, w0.w, hacc[e].w); hacc[e].w = fmaf(lv.y, w1.w, hacc[e].w);
                    hacc[e].w = fmaf(lv.z, w2.w, hacc[e].w); hacc[e].w = fmaf(lv.w, w3.w, hacc[e].w);
                }
            }
            __builtin_amdgcn_wave_barrier(); // latS reads done before next l overwrites
        }
    }

    // ---- h = silu(hacc) into bufS (sim region dead; wave-private) ----
    #pragma unroll
    for (int e = 0; e < EW; ++e) {
        float4 hv;
        hv.x = silu_f(hacc[e].x); hv.y = silu_f(hacc[e].y);
        hv.z = silu_f(hacc[e].z); hv.w = silu_f(hacc[e].w);
        *(float4*)&bufS[w][e][k0] = hv;
    }
    __builtin_amdgcn_wave_barrier();

    // ---- Phase 4: out[e][0..128) = h @ Wf2 + bf2 ----
    {
        int c0 = lane * 2;
        float2 acc[EW];
        float2 bias = *(const float2*)&bf2v[c0];
        #pragma unroll
        for (int e = 0; e < EW; ++e) acc[e] = bias;
        for (int i0 = 0; i0 < 256; i0 += 4) {
            float2 w0 = *(const float2*)&Wf2[(size_t)(i0 + 0) * 128 + c0];
            float2 w1 = *(const float2*)&Wf2[(size_t)(i0 + 1) * 128 + c0];
            float2 w2 = *(const float2*)&Wf2[(size_t)(i0 + 2) * 128 + c0];
            float2 w3 = *(const float2*)&Wf2[(size_t)(i0 + 3) * 128 + c0];
            #pragma unroll
            for (int e = 0; e < EW; ++e) {
                float4 hv = *(const float4*)&bufS[w][e][i0];
                acc[e].x = fmaf(hv.x, w0.x, acc[e].x); acc[e].x = fmaf(hv.y, w1.x, acc[e].x);
                acc[e].x = fmaf(hv.z, w2.x, acc[e].x); acc[e].x = fmaf(hv.w, w3.x, acc[e].x);
                acc[e].y = fmaf(hv.x, w0.y, acc[e].y); acc[e].y = fmaf(hv.y, w1.y, acc[e].y);
                acc[e].y = fmaf(hv.z, w2.y, acc[e].y); acc[e].y = fmaf(hv.w, w3.y, acc[e].y);
            }
        }
        #pragma unroll
        for (int e = 0; e < EW; ++e) {
            long eg = e0 + e;
            if (eg < n_edges) {
                out[eg * 128 + c0 + 0] = acc[e].x;
                out[eg * 128 + c0 + 1] = acc[e].y;
            }
        }
    }
    #undef LDC
    #undef LDN
}

extern "C" void kernel_launch(void* const* d_in, const int* in_sizes, int n_in,
                              void* d_out, int out_size, void* d_ws, size_t ws_size,
                              hipStream_t stream) {
    const float* x    = (const float*)d_in[0];
    // d_in[1] = active_edge_vector: unused by the reference
    const int* eidx   = (const int*)d_in[2];
    const float* wig  = (const float*)d_in[3];
    const float* Wc0  = (const float*)d_in[4];
    const float* bc0  = (const float*)d_in[5];
    const float* Wc1  = (const float*)d_in[6];
    const float* Wc2  = (const float*)d_in[7];
    const float* Wn0  = (const float*)d_in[8];
    const float* bn0  = (const float*)d_in[9];
    const float* Wn1  = (const float*)d_in[10];
    const float* Wn2  = (const float*)d_in[11];
    const float* Ws0  = (const float*)d_in[12];
    const float* bs0  = (const float*)d_in[13];
    const float* Ws1  = (const float*)d_in[14];
    const float* bs1  = (const float*)d_in[15];
    const float* Ws2  = (const float*)d_in[16];
    const float* bs2  = (const float*)d_in[17];
    const float* Wf1  = (const float*)d_in[18];
    const float* bf1  = (const float*)d_in[19];
    const float* Wf2  = (const float*)d_in[20];
    const float* bf2v = (const float*)d_in[21];
    float* out = (float*)d_out;

    const int n_nodes = in_sizes[0] / NFEAT;
    const int n_edges = in_sizes[2] / 2;
    const size_t cn = (size_t)n_nodes * NFEAT;

    const int blkA = 256;
    const int grdA = (int)((cn + blkA - 1) / blkA);
    const int grdB = (n_edges + EB - 1) / EB;

    if (ws_size >= cn * 2 * sizeof(float)) {
        float* C  = (float*)d_ws;
        float* Nh = C + cn;
        node_kernel<true><<<grdA, blkA, 0, stream>>>(x, Wc0, bc0, Wc1, Wc2,
                                                     Wn0, bn0, Wn1, Wn2,
                                                     (void*)C, (void*)Nh, n_nodes);
        edge_kernel<true><<<grdB, 256, 0, stream>>>((const void*)C, (const void*)Nh,
                                                    eidx, wig,
                                                    Ws0, bs0, Ws1, bs1, Ws2, bs2,
                                                    Wf1, bf1, Wf2, bf2v,
                                                    out, n_edges);
    } else {
        __half* C  = (__half*)d_ws;
        __half* Nh = C + cn;
        node_kernel<false><<<grdA, blkA, 0, stream>>>(x, Wc0, bc0, Wc1, Wc2,
                                                      Wn0, bn0, Wn1, Wn2,
                                                      (void*)C, (void*)Nh, n_nodes);
        edge_kernel<false><<<grdB, 256, 0, stream>>>((const void*)C, (const void*)Nh,
                                                     eidx, wig,
                                                     Ws0, bs0, Ws1, bs1, Ws2, bs2,
                                                     Wf1, bf1, Wf2, bf2v,
                                                     out, n_edges);
    }
}

// Round 2
// 1157.669 us; speedup vs baseline: 2.7547x; 2.7547x over previous
//
#include <hip/hip_runtime.h>
#include <hip/hip_fp16.h>
#include <math.h>

// SO2_Attention — Round 5: f16 MFMA rewrite of the 3-GEMM MLP chain.
// Evidence (round 1): VALUBusy 61% / MfmaUtil 0 / HBM 3.4% -> f32 VALU-bound
// (floor 1.9ms) + per-wave 647KB weight re-stream from L2 (1.6ms). absmax
// 0.0039 proves the f16 workspace branch is active and passes -> f16 MFMA ok.
//
// Structure: block = 32 edges, 4 waves.
//  - Phase 1 writes sim[32][256] (pad 240..255 = 0) in MFMA A-frag order (LDS).
//  - Weights pre-packed (pack_kernel, once per launch) into B-frag order f16
//    in workspace: coalesced 16B/lane loads, 317KB/block total weight traffic.
//  - GEMM1 (3 block-diag subs, K=64/96/80->96) -> latF -> GEMM2 (K=384) ->
//    hF (aliases simF) -> GEMM3 (K=256) -> out.
//  - LDS 40KB -> 4 blocks/CU (16 waves). MFMA layout: A lane&15=m,
//    k=(lane>>4)*8+i; B lane&15=n, same k; D col=lane&15, row=(lane>>4)*4+reg.

#define NFEAT 240

typedef _Float16 f16;
typedef _Float16 f16x8 __attribute__((ext_vector_type(8)));
typedef float f32x4 __attribute__((ext_vector_type(4)));

__device__ __forceinline__ float silu_f(float x) {
    return x / (1.0f + __expf(-x));
}

// frag element index for value at (edge e in 0..31, column kk within 32-wide
// k-step s) in a frag-ordered buffer: [fragIdx = s*2 + (e>>4)][lane][i]
__device__ __forceinline__ int frag_idx(int s, int e, int kk) {
    return ((s * 2 + (e >> 4)) * 64 + (((kk >> 3) << 4) | (e & 15))) * 8 + (kk & 7);
}

// ---------------- Kernel A: per-node e3nn linear (center + neigh) -------------
template <bool F32>
__global__ void node_kernel(const float* __restrict__ x,
                            const float* __restrict__ Wc0, const float* __restrict__ bc0,
                            const float* __restrict__ Wc1, const float* __restrict__ Wc2,
                            const float* __restrict__ Wn0, const float* __restrict__ bn0,
                            const float* __restrict__ Wn1, const float* __restrict__ Wn2,
                            void* __restrict__ Cp, void* __restrict__ Np,
                            int n_nodes)
{
    int t = blockIdx.x * blockDim.x + threadIdx.x;
    int total = n_nodes * NFEAT;
    if (t >= total) return;
    int n = t / NFEAT;
    int j = t - n * NFEAT;
    const float* xr = x + (size_t)n * NFEAT;
    float ac = 0.f, an = 0.f;
    if (j < 64) {
        #pragma unroll 8
        for (int m = 0; m < 64; ++m) {
            float xv = xr[m];
            ac = fmaf(xv, Wc0[m * 64 + j], ac);
            an = fmaf(xv, Wn0[m * 64 + j], an);
        }
        ac = ac * 0.125f + bc0[j];
        an = an * 0.125f + bn0[j];
    } else if (j < 160) {
        int s = j - 64; int k = s / 3; int d = s - 3 * k;
        #pragma unroll 8
        for (int m = 0; m < 32; ++m) {
            float xv = xr[64 + m * 3 + d];
            ac = fmaf(xv, Wc1[m * 32 + k], ac);
            an = fmaf(xv, Wn1[m * 32 + k], an);
        }
        const float s32 = 0.17677669529663687f; // 1/sqrt(32)
        ac *= s32; an *= s32;
    } else {
        int s = j - 160; int k = s / 5; int d = s - 5 * k;
        #pragma unroll 8
        for (int m = 0; m < 16; ++m) {
            float xv = xr[160 + m * 5 + d];
            ac = fmaf(xv, Wc2[m * 16 + k], ac);
            an = fmaf(xv, Wn2[m * 16 + k], an);
        }
        ac *= 0.25f; an *= 0.25f;
    }
    if (F32) {
        ((float*)Cp)[t] = ac;
        ((float*)Np)[t] = an;
    } else {
        ((__half*)Cp)[t] = __float2half(ac);
        ((__half*)Np)[t] = __float2half(an);
    }
}

// ---------------- Kernel P: pack weights into f16 B-fragment order ------------
// Layout in P (halves):
//  [0,       32768)  WsP : 8 ksteps x 8 ntiles   (sub K-pad: Ws2 rows 80..95=0)
//  [32768,  131072)  Wf1P: 12 ksteps x 16 ntiles
//  [131072, 163840)  Wf2P: 8 ksteps x 8 ntiles
// Frag element: [fi][lane][i], B[k][n]: k = s*32 + (lane>>4)*8 + i,
//                               n = nt*16 + (lane&15).
__global__ void pack_kernel(const float* __restrict__ Ws0, const float* __restrict__ Ws1,
                            const float* __restrict__ Ws2, const float* __restrict__ Wf1,
                            const float* __restrict__ Wf2, f16* __restrict__ P)
{
    int idx = blockIdx.x * 256 + threadIdx.x;
    if (idx >= 163840) return;
    int lane = (idx >> 3) & 63;
    int i = idx & 7;
    int kc = ((lane >> 4) << 3) + i;   // k within 32-wide step
    int nl = lane & 15;                // n within 16-wide tile
    float v;
    if (idx < 32768) {
        int fi = idx >> 9; int s = fi >> 3; int nt = fi & 7;
        int l = (s < 2) ? 0 : ((s < 5) ? 1 : 2);
        int s0 = (l == 0) ? 0 : ((l == 1) ? 2 : 5);
        int K = (l == 0) ? 64 : ((l == 1) ? 96 : 80);
        const float* W = (l == 0) ? Ws0 : ((l == 1) ? Ws1 : Ws2);
        int k = (s - s0) * 32 + kc;
        int col = (nt << 4) | nl;
        v = (k < K) ? W[k * 128 + col] : 0.f;
    } else if (idx < 131072) {
        int fi = (idx - 32768) >> 9; int s = fi >> 4; int nt = fi & 15;
        int k = s * 32 + kc;
        int col = (nt << 4) | nl;
        v = Wf1[k * 256 + col];
    } else {
        int fi = (idx - 131072) >> 9; int s = fi >> 3; int nt = fi & 7;
        int k = s * 32 + kc;
        int col = (nt << 4) | nl;
        v = Wf2[k * 128 + col];
    }
    P[idx] = (f16)v;
}

// ---------------- Kernel B (MFMA): fused per-edge pipeline --------------------
// 256 threads = 4 waves; block owns 32 edges (2 m-tiles of 16).
__global__ __launch_bounds__(256, 4) void edge_mfma(
    const f16* __restrict__ C, const f16* __restrict__ Nn,
    const int* __restrict__ eidx, const float* __restrict__ wig,
    const f16* __restrict__ P,
    const float* __restrict__ bs0, const float* __restrict__ bs1,
    const float* __restrict__ bs2, const float* __restrict__ bf1,
    const float* __restrict__ bf2v,
    float* __restrict__ out, int n_edges)
{
    __shared__ __align__(16) f16 latF[24 * 512];  // 24 KB: lat frags (12 ks x 2 mt)
    __shared__ __align__(16) f16 simF[16 * 512];  // 16 KB: sim frags; later hF

    const int tid = threadIdx.x;
    const int lane = tid & 63;
    const int w = tid >> 6;
    const long e0 = (long)blockIdx.x * 32;

    // ---- zero sim pad (cols 240..255 -> frags 14,15 lanes 32..63) ----
    {
        int mt = tid >> 7;           // 0..1
        int r = tid & 127;
        int l2 = 32 + (r >> 2);      // lane slot 32..63
        int wd = r & 3;
        ((float*)simF)[((14 + mt) * 64 + l2) * 4 + wd] = 0.f;
    }

    // ---- Phase 1: sim -> simF (f16, frag order), block-wide task split ----
    // l=0: 32 edges x 64 cols = 2048 tasks
    #pragma unroll
    for (int it = 0; it < 8; ++it) {
        int t = it * 256 + tid;
        int e = t >> 6, j = t & 63;
        long eg = e0 + e;
        bool a = eg < n_edges;
        int i0 = a ? eidx[eg] : 0;
        int i1 = a ? eidx[(long)n_edges + eg] : 0;
        float c = (float)C[(size_t)i0 * NFEAT + j];
        float n = (float)Nn[(size_t)i1 * NFEAT + j];
        simF[frag_idx(j >> 5, e, j & 31)] = (f16)(c * n);
    }
    // l=1: 32 x 32 = 1024 tasks (3 outputs each)
    #pragma unroll
    for (int it = 0; it < 4; ++it) {
        int t = it * 256 + tid;
        int e = t >> 5, m = t & 31;
        long eg = e0 + e;
        bool a = eg < n_edges;
        int i0 = a ? eidx[eg] : 0;
        int i1 = a ? eidx[(long)n_edges + eg] : 0;
        const float* wg = wig + (a ? eg : 0) * 81;
        int base = 64 + m * 3;
        const f16* cr = C + (size_t)i0 * NFEAT + base;
        const f16* nr = Nn + (size_t)i1 * NFEAT + base;
        float c0 = cr[0], c1 = cr[1], c2 = cr[2];
        float n0 = nr[0], n1 = nr[1], n2 = nr[2];
        #pragma unroll
        for (int q = 0; q < 3; ++q) {
            float r0 = wg[(1 + 0) * 9 + (1 + q)];
            float r1 = wg[(1 + 1) * 9 + (1 + q)];
            float r2 = wg[(1 + 2) * 9 + (1 + q)];
            float cq = c0 * r0 + c1 * r1 + c2 * r2;
            float nq = n0 * r0 + n1 * r1 + n2 * r2;
            int j = base + q;
            simF[frag_idx(j >> 5, e, j & 31)] = (f16)(cq * nq);
        }
    }
    // l=2: 32 x 16 = 512 tasks (5 outputs each)
    #pragma unroll
    for (int it = 0; it < 2; ++it) {
        int t = it * 256 + tid;
        int e = t >> 4, m = t & 15;
        long eg = e0 + e;
        bool a = eg < n_edges;
        int i0 = a ? eidx[eg] : 0;
        int i1 = a ? eidx[(long)n_edges + eg] : 0;
        const float* wg = wig + (a ? eg : 0) * 81;
        int base = 160 + m * 5;
        const f16* cr = C + (size_t)i0 * NFEAT + base;
        const f16* nr = Nn + (size_t)i1 * NFEAT + base;
        float c[5], n[5];
        #pragma unroll
        for (int d = 0; d < 5; ++d) { c[d] = cr[d]; n[d] = nr[d]; }
        #pragma unroll
        for (int q = 0; q < 5; ++q) {
            float cq = 0.f, nq = 0.f;
            #pragma unroll
            for (int d = 0; d < 5; ++d) {
                float rv = wg[(4 + d) * 9 + (4 + q)];
                cq = fmaf(c[d], rv, cq);
                nq = fmaf(n[d], rv, nq);
            }
            int j = base + q;
            simF[frag_idx(j >> 5, e, j & 31)] = (f16)(cq * nq);
        }
    }
    __syncthreads();

    const f16* WsP  = P;
    const f16* Wf1P = P + 32768;
    const f16* Wf2P = P + 131072;

    // ---- GEMM1: lat[32][384] = silu(sim @ Ws + bs), block-diagonal ----
    {
        const int s0a[3] = {0, 2, 5};
        const int sca[3] = {2, 3, 3};
        const float* bsa[3] = { bs0, bs1, bs2 };
        #pragma unroll
        for (int l = 0; l < 3; ++l) {
            f32x4 a00 = {0.f, 0.f, 0.f, 0.f};
            f32x4 a01 = a00, a10 = a00, a11 = a00;
            #pragma unroll
            for (int s_ = 0; s_ < sca[l]; ++s_) {
                int s = s0a[l] + s_;
                f16x8 A0 = *(const f16x8*)&simF[((s * 2 + 0) * 64 + lane) * 8];
                f16x8 A1 = *(const f16x8*)&simF[((s * 2 + 1) * 64 + lane) * 8];
                f16x8 B0 = *(const f16x8*)&WsP[((s * 8 + 2 * w + 0) * 64 + lane) * 8];
                f16x8 B1 = *(const f16x8*)&WsP[((s * 8 + 2 * w + 1) * 64 + lane) * 8];
                a00 = __builtin_amdgcn_mfma_f32_16x16x32_f16(A0, B0, a00, 0, 0, 0);
                a10 = __builtin_amdgcn_mfma_f32_16x16x32_f16(A1, B0, a10, 0, 0, 0);
                a01 = __builtin_amdgcn_mfma_f32_16x16x32_f16(A0, B1, a01, 0, 0, 0);
                a11 = __builtin_amdgcn_mfma_f32_16x16x32_f16(A1, B1, a11, 0, 0, 0);
            }
            #pragma unroll
            for (int ntl = 0; ntl < 2; ++ntl) {
                int c128 = (2 * w + ntl) * 16 + (lane & 15);
                float bias = bsa[l][c128];
                int n = l * 128 + c128;
                #pragma unroll
                for (int mt = 0; mt < 2; ++mt) {
                    f32x4 av = ntl ? (mt ? a11 : a01) : (mt ? a10 : a00);
                    #pragma unroll
                    for (int r = 0; r < 4; ++r) {
                        int e = mt * 16 + ((lane >> 4) << 2) + r;
                        latF[frag_idx(n >> 5, e, n & 31)] = (f16)silu_f(av[r] + bias);
                    }
                }
            }
        }
    }
    __syncthreads();

    // ---- GEMM2: h[32][256] = silu(lat @ Wf1 + bf1) -> hF (aliases simF) ----
    {
        f32x4 acc[2][4];
        #pragma unroll
        for (int mt = 0; mt < 2; ++mt)
            #pragma unroll
            for (int j = 0; j < 4; ++j) {
                f32x4 z = {0.f, 0.f, 0.f, 0.f};
                acc[mt][j] = z;
            }
        for (int s = 0; s < 12; ++s) {
            f16x8 A0 = *(const f16x8*)&latF[((s * 2 + 0) * 64 + lane) * 8];
            f16x8 A1 = *(const f16x8*)&latF[((s * 2 + 1) * 64 + lane) * 8];
            #pragma unroll
            for (int j = 0; j < 4; ++j) {
                f16x8 B = *(const f16x8*)&Wf1P[((s * 16 + 4 * w + j) * 64 + lane) * 8];
                acc[0][j] = __builtin_amdgcn_mfma_f32_16x16x32_f16(A0, B, acc[0][j], 0, 0, 0);
                acc[1][j] = __builtin_amdgcn_mfma_f32_16x16x32_f16(A1, B, acc[1][j], 0, 0, 0);
            }
        }
        #pragma unroll
        for (int j = 0; j < 4; ++j) {
            int col = (4 * w + j) * 16 + (lane & 15);
            float bias = bf1[col];
            #pragma unroll
            for (int mt = 0; mt < 2; ++mt) {
                #pragma unroll
                for (int r = 0; r < 4; ++r) {
                    int e = mt * 16 + ((lane >> 4) << 2) + r;
                    simF[frag_idx(col >> 5, e, col & 31)] = (f16)silu_f(acc[mt][j][r] + bias);
                }
            }
        }
    }
    __syncthreads();

    // ---- GEMM3: out[32][128] = h @ Wf2 + bf2 ----
    {
        f32x4 acc[2][2];
        #pragma unroll
        for (int mt = 0; mt < 2; ++mt)
            #pragma unroll
            for (int j = 0; j < 2; ++j) {
                f32x4 z = {0.f, 0.f, 0.f, 0.f};
                acc[mt][j] = z;
            }
        for (int s = 0; s < 8; ++s) {
            f16x8 A0 = *(const f16x8*)&simF[((s * 2 + 0) * 64 + lane) * 8];
            f16x8 A1 = *(const f16x8*)&simF[((s * 2 + 1) * 64 + lane) * 8];
            #pragma unroll
            for (int j = 0; j < 2; ++j) {
                f16x8 B = *(const f16x8*)&Wf2P[((s * 8 + 2 * w + j) * 64 + lane) * 8];
                acc[0][j] = __builtin_amdgcn_mfma_f32_16x16x32_f16(A0, B, acc[0][j], 0, 0, 0);
                acc[1][j] = __builtin_amdgcn_mfma_f32_16x16x32_f16(A1, B, acc[1][j], 0, 0, 0);
            }
        }
        #pragma unroll
        for (int j = 0; j < 2; ++j) {
            int col = (2 * w + j) * 16 + (lane & 15);
            float bias = bf2v[col];
            #pragma unroll
            for (int mt = 0; mt < 2; ++mt) {
                #pragma unroll
                for (int r = 0; r < 4; ++r) {
                    int e = mt * 16 + ((lane >> 4) << 2) + r;
                    long eg = e0 + e;
                    if (eg < n_edges) out[eg * 128 + col] = acc[mt][j][r] + bias;
                }
            }
        }
    }
}

// ---------------- Fallback: round-4 f16 VALU edge kernel ----------------------
#define EW 6
#define WPB 4
#define EB (EW * WPB)
#define BUFW 260
#define LATW 132

__global__ __launch_bounds__(256, 4) void edge_kernel_f16(
    const void* __restrict__ Cp, const void* __restrict__ Np,
    const int* __restrict__ eidx, const float* __restrict__ wig,
    const float* __restrict__ Ws0, const float* __restrict__ bs0,
    const float* __restrict__ Ws1, const float* __restrict__ bs1,
    const float* __restrict__ Ws2, const float* __restrict__ bs2,
    const float* __restrict__ Wf1, const float* __restrict__ bf1,
    const float* __restrict__ Wf2, const float* __restrict__ bf2v,
    float* __restrict__ out, int n_edges)
{
    __shared__ __align__(16) float bufS[WPB][EW][BUFW];
    __shared__ __align__(16) float latS[WPB][EW][LATW];

    const int w = threadIdx.x >> 6;
    const int lane = threadIdx.x & 63;
    const long e0 = (long)blockIdx.x * EB + (long)w * EW;

    const __half* Chrow[EW];
    const __half* Nhrow[EW];
    bool act[EW];
    #pragma unroll
    for (int e = 0; e < EW; ++e) {
        long eg = e0 + e;
        act[e] = eg < n_edges;
        long i0 = 0, i1 = 0;
        if (act[e]) { i0 = eidx[eg]; i1 = eidx[(long)n_edges + eg]; }
        Chrow[e] = (const __half*)Cp + i0 * NFEAT;
        Nhrow[e] = (const __half*)Np + i1 * NFEAT;
    }
    #define LDC(e, i) (__half2float(Chrow[e][i]))
    #define LDN(e, i) (__half2float(Nhrow[e][i]))

    #pragma unroll
    for (int e = 0; e < EW; ++e) {
        if (act[e]) {
            float c = LDC(e, lane);
            float n = LDN(e, lane);
            bufS[w][e][lane] = c * n;
        }
    }
    #pragma unroll
    for (int it = 0; it < 3; ++it) {
        int t = it * 64 + lane;
        int e = t >> 5;
        int m = t & 31;
        if (act[e]) {
            long eg = e0 + e;
            const float* wg = wig + eg * 81;
            int base = 64 + m * 3;
            float c0 = LDC(e, base + 0), c1 = LDC(e, base + 1), c2 = LDC(e, base + 2);
            float n0 = LDN(e, base + 0), n1 = LDN(e, base + 1), n2 = LDN(e, base + 2);
            #pragma unroll
            for (int q = 0; q < 3; ++q) {
                float r0 = wg[(1 + 0) * 9 + (1 + q)];
                float r1 = wg[(1 + 1) * 9 + (1 + q)];
                float r2 = wg[(1 + 2) * 9 + (1 + q)];
                float cq = c0 * r0 + c1 * r1 + c2 * r2;
                float nq = n0 * r0 + n1 * r1 + n2 * r2;
                bufS[w][e][base + q] = cq * nq;
            }
        }
    }
    #pragma unroll
    for (int it = 0; it < 2; ++it) {
        int t = it * 64 + lane;
        if (t < 96) {
            int e = t >> 4;
            int m = t & 15;
            if (act[e]) {
                long eg = e0 + e;
                const float* wg = wig + eg * 81;
                int base = 160 + m * 5;
                float c[5], n[5];
                #pragma unroll
                for (int d = 0; d < 5; ++d) { c[d] = LDC(e, base + d); n[d] = LDN(e, base + d); }
                #pragma unroll
                for (int q = 0; q < 5; ++q) {
                    float cq = 0.f, nq = 0.f;
                    #pragma unroll
                    for (int d = 0; d < 5; ++d) {
                        float rv = wg[(4 + d) * 9 + (4 + q)];
                        cq = fmaf(c[d], rv, cq);
                        nq = fmaf(n[d], rv, nq);
                    }
                    bufS[w][e][base + q] = cq * nq;
                }
            }
        }
    }
    __builtin_amdgcn_wave_barrier();

    const int k0 = lane * 4;
    float4 hacc[EW];
    {
        float4 hb = *(const float4*)&bf1[k0];
        #pragma unroll
        for (int e = 0; e < EW; ++e) hacc[e] = hb;
    }
    {
        const float* Wsl[3] = { Ws0, Ws1, Ws2 };
        const float* bsl[3] = { bs0, bs1, bs2 };
        const int Kl[3] = { 64, 96, 80 };
        const int offl[3] = { 0, 64, 160 };
        #pragma unroll
        for (int l = 0; l < 3; ++l) {
            const float* W = Wsl[l];
            const int K = Kl[l];
            const int off = offl[l];
            const int c0 = lane * 2;
            float acc0[EW], acc1[EW];
            {
                float b0v = bsl[l][c0];
                float b1v = bsl[l][c0 + 1];
                #pragma unroll
                for (int e = 0; e < EW; ++e) { acc0[e] = b0v; acc1[e] = b1v; }
            }
            for (int i0 = 0; i0 < K; i0 += 4) {
                float2 w0 = *(const float2*)&W[(i0 + 0) * 128 + c0];
                float2 w1 = *(const float2*)&W[(i0 + 1) * 128 + c0];
                float2 w2 = *(const float2*)&W[(i0 + 2) * 128 + c0];
                float2 w3 = *(const float2*)&W[(i0 + 3) * 128 + c0];
                #pragma unroll
                for (int e = 0; e < EW; ++e) {
                    float4 sv = *(const float4*)&bufS[w][e][off + i0];
                    acc0[e] = fmaf(sv.x, w0.x, acc0[e]);
                    acc0[e] = fmaf(sv.y, w1.x, acc0[e]);
                    acc0[e] = fmaf(sv.z, w2.x, acc0[e]);
                    acc0[e] = fmaf(sv.w, w3.x, acc0[e]);
                    acc1[e] = fmaf(sv.x, w0.y, acc1[e]);
                    acc1[e] = fmaf(sv.y, w1.y, acc1[e]);
                    acc1[e] = fmaf(sv.z, w2.y, acc1[e]);
                    acc1[e] = fmaf(sv.w, w3.y, acc1[e]);
                }
            }
            #pragma unroll
            for (int e = 0; e < EW; ++e) {
                float2 lv;
                lv.x = silu_f(acc0[e]);
                lv.y = silu_f(acc1[e]);
                *(float2*)&latS[w][e][c0] = lv;
            }
            __builtin_amdgcn_wave_barrier();

            const float* W1 = Wf1 + (size_t)l * 128 * 256;
            for (int i0 = 0; i0 < 128; i0 += 4) {
                float4 w0 = *(const float4*)&W1[(size_t)(i0 + 0) * 256 + k0];
                float4 w1 = *(const float4*)&W1[(size_t)(i0 + 1) * 256 + k0];
                float4 w2 = *(const float4*)&W1[(size_t)(i0 + 2) * 256 + k0];
                float4 w3 = *(const float4*)&W1[(size_t)(i0 + 3) * 256 + k0];
                #pragma unroll
                for (int e = 0; e < EW; ++e) {
                    float4 lv = *(const float4*)&latS[w][e][i0];
                    hacc[e].x = fmaf(lv.x, w0.x, hacc[e].x); hacc[e].x = fmaf(lv.y, w1.x, hacc[e].x);
                    hacc[e].x = fmaf(lv.z, w2.x, hacc[e].x); hacc[e].x = fmaf(lv.w, w3.x, hacc[e].x);
                    hacc[e].y = fmaf(lv.x, w0.y, hacc[e].y); hacc[e].y = fmaf(lv.y, w1.y, hacc[e].y);
                    hacc[e].y = fmaf(lv.z, w2.y, hacc[e].y); hacc[e].y = fmaf(lv.w, w3.y, hacc[e].y);
                    hacc[e].z = fmaf(lv.x, w0.z, hacc[e].z); hacc[e].z = fmaf(lv.y, w1.z, hacc[e].z);
                    hacc[e].z = fmaf(lv.z, w2.z, hacc[e].z); hacc[e].z = fmaf(lv.w, w3.z, hacc[e].z);
                    hacc[e].w = fmaf(lv.x, w0.w, hacc[e].w); hacc[e].w = fmaf(lv.y, w1.w, hacc[e].w);
                    hacc[e].w = fmaf(lv.z, w2.w, hacc[e].w); hacc[e].w = fmaf(lv.w, w3.w, hacc[e].w);
                }
            }
            __builtin_amdgcn_wave_barrier();
        }
    }
    #pragma unroll
    for (int e = 0; e < EW; ++e) {
        float4 hv;
        hv.x = silu_f(hacc[e].x); hv.y = silu_f(hacc[e].y);
        hv.z = silu_f(hacc[e].z); hv.w = silu_f(hacc[e].w);
        *(float4*)&bufS[w][e][k0] = hv;
    }
    __builtin_amdgcn_wave_barrier();
    {
        int c0 = lane * 2;
        float2 acc[EW];
        float2 bias = *(const float2*)&bf2v[c0];
        #pragma unroll
        for (int e = 0; e < EW; ++e) acc[e] = bias;
        for (int i0 = 0; i0 < 256; i0 += 4) {
            float2 w0 = *(const float2*)&Wf2[(size_t)(i0 + 0) * 128 + c0];
            float2 w1 = *(const float2*)&Wf2[(size_t)(i0 + 1) * 128 + c0];
            float2 w2 = *(const float2*)&Wf2[(size_t)(i0 + 2) * 128 + c0];
            float2 w3 = *(const float2*)&Wf2[(size_t)(i0 + 3) * 128 + c0];
            #pragma unroll
            for (int e = 0; e < EW; ++e) {
                float4 hv = *(const float4*)&bufS[w][e][i0];
                acc[e].x = fmaf(hv.x, w0.x, acc[e].x); acc[e].x = fmaf(hv.y, w1.x, acc[e].x);
                acc[e].x = fmaf(hv.z, w2.x, acc[e].x); acc[e].x = fmaf(hv.w, w3.x, acc[e].x);
                acc[e].y = fmaf(hv.x, w0.y, acc[e].y); acc[e].y = fmaf(hv.y, w1.y, acc[e].y);
                acc[e].y = fmaf(hv.z, w2.y, acc[e].y); acc[e].y = fmaf(hv.w, w3.y, acc[e].y);
            }
        }
        #pragma unroll
        for (int e = 0; e < EW; ++e) {
            long eg = e0 + e;
            if (eg < n_edges) {
                out[eg * 128 + c0 + 0] = acc[e].x;
                out[eg * 128 + c0 + 1] = acc[e].y;
            }
        }
    }
    #undef LDC
    #undef LDN
}

extern "C" void kernel_launch(void* const* d_in, const int* in_sizes, int n_in,
                              void* d_out, int out_size, void* d_ws, size_t ws_size,
                              hipStream_t stream) {
    const float* x    = (const float*)d_in[0];
    // d_in[1] = active_edge_vector: unused by the reference
    const int* eidx   = (const int*)d_in[2];
    const float* wig  = (const float*)d_in[3];
    const float* Wc0  = (const float*)d_in[4];
    const float* bc0  = (const float*)d_in[5];
    const float* Wc1  = (const float*)d_in[6];
    const float* Wc2  = (const float*)d_in[7];
    const float* Wn0  = (const float*)d_in[8];
    const float* bn0  = (const float*)d_in[9];
    const float* Wn1  = (const float*)d_in[10];
    const float* Wn2  = (const float*)d_in[11];
    const float* Ws0  = (const float*)d_in[12];
    const float* bs0  = (const float*)d_in[13];
    const float* Ws1  = (const float*)d_in[14];
    const float* bs1  = (const float*)d_in[15];
    const float* Ws2  = (const float*)d_in[16];
    const float* bs2  = (const float*)d_in[17];
    const float* Wf1  = (const float*)d_in[18];
    const float* bf1  = (const float*)d_in[19];
    const float* Wf2  = (const float*)d_in[20];
    const float* bf2v = (const float*)d_in[21];
    float* out = (float*)d_out;

    const int n_nodes = in_sizes[0] / NFEAT;
    const int n_edges = in_sizes[2] / 2;
    const size_t cn = (size_t)n_nodes * NFEAT;

    const int blkA = 256;
    const int grdA = (int)((cn + blkA - 1) / blkA);

    const size_t needM = cn * 2 * sizeof(__half) + (size_t)163840 * sizeof(f16);

    if (ws_size >= needM) {
        __half* C  = (__half*)d_ws;
        __half* Nh = C + cn;
        f16* P = (f16*)((char*)d_ws + cn * 2 * sizeof(__half));
        node_kernel<false><<<grdA, blkA, 0, stream>>>(x, Wc0, bc0, Wc1, Wc2,
                                                      Wn0, bn0, Wn1, Wn2,
                                                      (void*)C, (void*)Nh, n_nodes);
        pack_kernel<<<640, 256, 0, stream>>>(Ws0, Ws1, Ws2, Wf1, Wf2, P);
        const int grdM = (n_edges + 31) / 32;
        edge_mfma<<<grdM, 256, 0, stream>>>((const f16*)C, (const f16*)Nh,
                                            eidx, wig, P,
                                            bs0, bs1, bs2, bf1, bf2v,
                                            out, n_edges);
    } else {
        __half* C  = (__half*)d_ws;
        __half* Nh = C + cn;
        node_kernel<false><<<grdA, blkA, 0, stream>>>(x, Wc0, bc0, Wc1, Wc2,
                                                      Wn0, bn0, Wn1, Wn2,
                                                      (void*)C, (void*)Nh, n_nodes);
        const int grdB = (n_edges + EB - 1) / EB;
        edge_kernel_f16<<<grdB, 256, 0, stream>>>((const void*)C, (const void*)Nh,
                                                  eidx, wig,
                                                  Ws0, bs0, Ws1, bs1, Ws2, bs2,
                                                  Wf1, bf1, Wf2, bf2v,
                                                  out, n_edges);
    }
}

// Round 3
// 1037.810 us; speedup vs baseline: 3.0729x; 1.1155x over previous
//
#include <hip/hip_runtime.h>
#include <hip/hip_fp16.h>
#include <math.h>

// SO2_Attention — Round 6.
// Evidence (round 2): edge_mfma 608us, VALUBusy 44%, MfmaUtil 11.7%, HBM 13%,
// SQ_LDS_BANK_CONFLICT 2.7e7 (phase-1 frag scatter stores hit a 4-bank column).
// Bench-vs-rocprof gap of 549us appeared when pack_kernel became a 3rd launch.
// Changes:
//  1. XOR bank swizzle (unit ^= (unit>>3)&7, 16B units) on ALL frag LDS accesses.
//  2. Phase-1 l=0 vectorized: f16x8 gathers + one ds_write_b128 per frag unit.
//  3. eidx cached in LDS once per block.
//  4. pack fused into prep_kernel (node blocks + 640 pack blocks, 1 dispatch).

#define NFEAT 240

typedef _Float16 f16;
typedef _Float16 f16x8 __attribute__((ext_vector_type(8)));
typedef float f32x4 __attribute__((ext_vector_type(4)));

__device__ __forceinline__ float silu_f(float x) {
    return x / (1.0f + __expf(-x));
}

// 16B-unit XOR swizzle: spreads frag slots across bank groups; bijective in frag.
__device__ __forceinline__ int swz_u(int u) { return u ^ ((u >> 3) & 7); }

// swizzled f16 element index for (k-step s, edge e, col-in-step kk)
__device__ __forceinline__ int fidx(int s, int e, int kk) {
    int u = (s * 2 + (e >> 4)) * 64 + (((kk >> 3) << 4) | (e & 15));
    return (swz_u(u) << 3) | (kk & 7);
}

// ---------------- node math (shared by prep + fallback path) ------------------
__device__ __forceinline__ void node_compute(
    const float* __restrict__ x,
    const float* __restrict__ Wc0, const float* __restrict__ bc0,
    const float* __restrict__ Wc1, const float* __restrict__ Wc2,
    const float* __restrict__ Wn0, const float* __restrict__ bn0,
    const float* __restrict__ Wn1, const float* __restrict__ Wn2,
    __half* __restrict__ Cp, __half* __restrict__ Np, int t)
{
    int n = t / NFEAT;
    int j = t - n * NFEAT;
    const float* xr = x + (size_t)n * NFEAT;
    float ac = 0.f, an = 0.f;
    if (j < 64) {
        #pragma unroll 8
        for (int m = 0; m < 64; ++m) {
            float xv = xr[m];
            ac = fmaf(xv, Wc0[m * 64 + j], ac);
            an = fmaf(xv, Wn0[m * 64 + j], an);
        }
        ac = ac * 0.125f + bc0[j];
        an = an * 0.125f + bn0[j];
    } else if (j < 160) {
        int s = j - 64; int k = s / 3; int d = s - 3 * k;
        #pragma unroll 8
        for (int m = 0; m < 32; ++m) {
            float xv = xr[64 + m * 3 + d];
            ac = fmaf(xv, Wc1[m * 32 + k], ac);
            an = fmaf(xv, Wn1[m * 32 + k], an);
        }
        const float s32 = 0.17677669529663687f; // 1/sqrt(32)
        ac *= s32; an *= s32;
    } else {
        int s = j - 160; int k = s / 5; int d = s - 5 * k;
        #pragma unroll 8
        for (int m = 0; m < 16; ++m) {
            float xv = xr[160 + m * 5 + d];
            ac = fmaf(xv, Wc2[m * 16 + k], ac);
            an = fmaf(xv, Wn2[m * 16 + k], an);
        }
        ac *= 0.25f; an *= 0.25f;
    }
    Cp[t] = __float2half(ac);
    Np[t] = __float2half(an);
}

// ---------------- Kernel A: node e3nn linear + weight pack (fused) ------------
// Blocks [0, grdNode): node center+neigh linear -> f16 C/N.
// Blocks [grdNode, grdNode+640): pack Ws/Wf1/Wf2 into f16 B-frag order in P.
//  P layout (halves): [0,32768) WsP (8 ks x 8 nt; Ws2 K-pad rows 80..95 = 0)
//                     [32768,131072) Wf1P (12 ks x 16 nt)
//                     [131072,163840) Wf2P (8 ks x 8 nt)
__global__ void prep_kernel(const float* __restrict__ x,
                            const float* __restrict__ Wc0, const float* __restrict__ bc0,
                            const float* __restrict__ Wc1, const float* __restrict__ Wc2,
                            const float* __restrict__ Wn0, const float* __restrict__ bn0,
                            const float* __restrict__ Wn1, const float* __restrict__ Wn2,
                            const float* __restrict__ Ws0, const float* __restrict__ Ws1,
                            const float* __restrict__ Ws2, const float* __restrict__ Wf1,
                            const float* __restrict__ Wf2,
                            __half* __restrict__ Cp, __half* __restrict__ Np,
                            f16* __restrict__ P, int n_nodes, int grdNode)
{
    if (blockIdx.x < (unsigned)grdNode) {
        int t = blockIdx.x * 256 + threadIdx.x;
        if (t >= n_nodes * NFEAT) return;
        node_compute(x, Wc0, bc0, Wc1, Wc2, Wn0, bn0, Wn1, Wn2, Cp, Np, t);
        return;
    }
    int idx = (blockIdx.x - grdNode) * 256 + threadIdx.x;
    if (idx >= 163840) return;
    int lane = (idx >> 3) & 63;
    int i = idx & 7;
    int kc = ((lane >> 4) << 3) + i;   // k within 32-wide step
    int nl = lane & 15;                // n within 16-wide tile
    float v;
    if (idx < 32768) {
        int fi = idx >> 9; int s = fi >> 3; int nt = fi & 7;
        int l = (s < 2) ? 0 : ((s < 5) ? 1 : 2);
        int s0 = (l == 0) ? 0 : ((l == 1) ? 2 : 5);
        int K = (l == 0) ? 64 : ((l == 1) ? 96 : 80);
        const float* W = (l == 0) ? Ws0 : ((l == 1) ? Ws1 : Ws2);
        int k = (s - s0) * 32 + kc;
        int col = (nt << 4) | nl;
        v = (k < K) ? W[k * 128 + col] : 0.f;
    } else if (idx < 131072) {
        int fi = (idx - 32768) >> 9; int s = fi >> 4; int nt = fi & 15;
        v = Wf1[(s * 32 + kc) * 256 + ((nt << 4) | nl)];
    } else {
        int fi = (idx - 131072) >> 9; int s = fi >> 3; int nt = fi & 7;
        v = Wf2[(s * 32 + kc) * 128 + ((nt << 4) | nl)];
    }
    P[idx] = (f16)v;
}

// ---------------- Kernel B (MFMA): fused per-edge pipeline --------------------
// 256 threads = 4 waves; block owns 32 edges (2 m-tiles of 16).
__global__ __launch_bounds__(256, 4) void edge_mfma(
    const f16* __restrict__ C, const f16* __restrict__ Nn,
    const int* __restrict__ eidx, const float* __restrict__ wig,
    const f16* __restrict__ P,
    const float* __restrict__ bs0, const float* __restrict__ bs1,
    const float* __restrict__ bs2, const float* __restrict__ bf1,
    const float* __restrict__ bf2v,
    float* __restrict__ out, int n_edges)
{
    __shared__ __align__(16) f16 latF[24 * 512];  // 24 KB: lat frags (12 ks x 2 mt)
    __shared__ __align__(16) f16 simF[16 * 512];  // 16 KB: sim frags; later hF
    __shared__ int i0s[32], i1s[32];

    const int tid = threadIdx.x;
    const int lane = tid & 63;
    const int laneS = lane ^ ((lane >> 3) & 7);   // swizzled A-frag slot
    const int w = tid >> 6;
    const long e0 = (long)blockIdx.x * 32;

    // ---- eidx -> LDS (once) ----
    if (tid < 32) {
        long eg = e0 + tid;
        bool a = eg < n_edges;
        i0s[tid] = a ? eidx[eg] : 0;
        i1s[tid] = a ? eidx[(long)n_edges + eg] : 0;
    }
    // ---- zero sim pad (cols 240..255 -> frags 14,15 slots 32..63) ----
    {
        int ul = tid >> 2;                       // 0..63 local unit
        int u = (14 + (ul >> 5)) * 64 + 32 + (ul & 31);
        ((float*)simF)[(swz_u(u) << 2) + (tid & 3)] = 0.f;
    }
    __syncthreads();

    // ---- Phase 1: sim -> simF (f16, swizzled frag order) ----
    // l=0: 32 edges x 8 col-groups = 256 tasks; one full frag unit per task.
    {
        int e = tid >> 3, kg = tid & 7;
        int i0 = i0s[e], i1 = i1s[e];
        f16x8 cv = *(const f16x8*)&C[(size_t)i0 * NFEAT + kg * 8];
        f16x8 nv = *(const f16x8*)&Nn[(size_t)i1 * NFEAT + kg * 8];
        f16x8 p = cv * nv;
        int u = ((kg >> 2) * 2 + (e >> 4)) * 64 + ((kg & 3) << 4) + (e & 15);
        *(f16x8*)&simF[swz_u(u) << 3] = p;
    }
    // l=1: 32 x 32 = 1024 tasks (3 outputs each)
    #pragma unroll
    for (int it = 0; it < 4; ++it) {
        int t = it * 256 + tid;
        int e = t >> 5, m = t & 31;
        long eg = e0 + e;
        bool a = eg < n_edges;
        const float* wg = wig + (a ? eg : 0) * 81;
        int base = 64 + m * 3;
        const f16* cr = C + (size_t)i0s[e] * NFEAT + base;
        const f16* nr = Nn + (size_t)i1s[e] * NFEAT + base;
        float c0 = cr[0], c1 = cr[1], c2 = cr[2];
        float n0 = nr[0], n1 = nr[1], n2 = nr[2];
        #pragma unroll
        for (int q = 0; q < 3; ++q) {
            float r0 = wg[(1 + 0) * 9 + (1 + q)];
            float r1 = wg[(1 + 1) * 9 + (1 + q)];
            float r2 = wg[(1 + 2) * 9 + (1 + q)];
            float cq = c0 * r0 + c1 * r1 + c2 * r2;
            float nq = n0 * r0 + n1 * r1 + n2 * r2;
            int j = base + q;
            simF[fidx(j >> 5, e, j & 31)] = (f16)(cq * nq);
        }
    }
    // l=2: 32 x 16 = 512 tasks (5 outputs each)
    #pragma unroll
    for (int it = 0; it < 2; ++it) {
        int t = it * 256 + tid;
        int e = t >> 4, m = t & 15;
        long eg = e0 + e;
        bool a = eg < n_edges;
        const float* wg = wig + (a ? eg : 0) * 81;
        int base = 160 + m * 5;
        const f16* cr = C + (size_t)i0s[e] * NFEAT + base;
        const f16* nr = Nn + (size_t)i1s[e] * NFEAT + base;
        float c[5], n[5];
        #pragma unroll
        for (int d = 0; d < 5; ++d) { c[d] = cr[d]; n[d] = nr[d]; }
        #pragma unroll
        for (int q = 0; q < 5; ++q) {
            float cq = 0.f, nq = 0.f;
            #pragma unroll
            for (int d = 0; d < 5; ++d) {
                float rv = wg[(4 + d) * 9 + (4 + q)];
                cq = fmaf(c[d], rv, cq);
                nq = fmaf(n[d], rv, nq);
            }
            int j = base + q;
            simF[fidx(j >> 5, e, j & 31)] = (f16)(cq * nq);
        }
    }
    __syncthreads();

    const f16* WsP  = P;
    const f16* Wf1P = P + 32768;
    const f16* Wf2P = P + 131072;

    // ---- GEMM1: lat[32][384] = silu(sim @ Ws + bs), block-diagonal ----
    {
        const int s0a[3] = {0, 2, 5};
        const int sca[3] = {2, 3, 3};
        const float* bsa[3] = { bs0, bs1, bs2 };
        #pragma unroll
        for (int l = 0; l < 3; ++l) {
            f32x4 a00 = {0.f, 0.f, 0.f, 0.f};
            f32x4 a01 = a00, a10 = a00, a11 = a00;
            #pragma unroll
            for (int s_ = 0; s_ < sca[l]; ++s_) {
                int s = s0a[l] + s_;
                f16x8 A0 = *(const f16x8*)&simF[(((s * 2 + 0) * 64 + laneS)) * 8];
                f16x8 A1 = *(const f16x8*)&simF[(((s * 2 + 1) * 64 + laneS)) * 8];
                f16x8 B0 = *(const f16x8*)&WsP[((s * 8 + 2 * w + 0) * 64 + lane) * 8];
                f16x8 B1 = *(const f16x8*)&WsP[((s * 8 + 2 * w + 1) * 64 + lane) * 8];
                a00 = __builtin_amdgcn_mfma_f32_16x16x32_f16(A0, B0, a00, 0, 0, 0);
                a10 = __builtin_amdgcn_mfma_f32_16x16x32_f16(A1, B0, a10, 0, 0, 0);
                a01 = __builtin_amdgcn_mfma_f32_16x16x32_f16(A0, B1, a01, 0, 0, 0);
                a11 = __builtin_amdgcn_mfma_f32_16x16x32_f16(A1, B1, a11, 0, 0, 0);
            }
            #pragma unroll
            for (int ntl = 0; ntl < 2; ++ntl) {
                int c128 = (2 * w + ntl) * 16 + (lane & 15);
                float bias = bsa[l][c128];
                int n = l * 128 + c128;
                #pragma unroll
                for (int mt = 0; mt < 2; ++mt) {
                    f32x4 av = ntl ? (mt ? a11 : a01) : (mt ? a10 : a00);
                    #pragma unroll
                    for (int r = 0; r < 4; ++r) {
                        int e = mt * 16 + ((lane >> 4) << 2) + r;
                        latF[fidx(n >> 5, e, n & 31)] = (f16)silu_f(av[r] + bias);
                    }
                }
            }
        }
    }
    __syncthreads();

    // ---- GEMM2: h[32][256] = silu(lat @ Wf1 + bf1) -> hF (aliases simF) ----
    {
        f32x4 acc[2][4];
        #pragma unroll
        for (int mt = 0; mt < 2; ++mt)
            #pragma unroll
            for (int j = 0; j < 4; ++j) {
                f32x4 z = {0.f, 0.f, 0.f, 0.f};
                acc[mt][j] = z;
            }
        for (int s = 0; s < 12; ++s) {
            f16x8 A0 = *(const f16x8*)&latF[(((s * 2 + 0) * 64 + laneS)) * 8];
            f16x8 A1 = *(const f16x8*)&latF[(((s * 2 + 1) * 64 + laneS)) * 8];
            #pragma unroll
            for (int j = 0; j < 4; ++j) {
                f16x8 B = *(const f16x8*)&Wf1P[((s * 16 + 4 * w + j) * 64 + lane) * 8];
                acc[0][j] = __builtin_amdgcn_mfma_f32_16x16x32_f16(A0, B, acc[0][j], 0, 0, 0);
                acc[1][j] = __builtin_amdgcn_mfma_f32_16x16x32_f16(A1, B, acc[1][j], 0, 0, 0);
            }
        }
        #pragma unroll
        for (int j = 0; j < 4; ++j) {
            int col = (4 * w + j) * 16 + (lane & 15);
            float bias = bf1[col];
            #pragma unroll
            for (int mt = 0; mt < 2; ++mt) {
                #pragma unroll
                for (int r = 0; r < 4; ++r) {
                    int e = mt * 16 + ((lane >> 4) << 2) + r;
                    simF[fidx(col >> 5, e, col & 31)] = (f16)silu_f(acc[mt][j][r] + bias);
                }
            }
        }
    }
    __syncthreads();

    // ---- GEMM3: out[32][128] = h @ Wf2 + bf2 ----
    {
        f32x4 acc[2][2];
        #pragma unroll
        for (int mt = 0; mt < 2; ++mt)
            #pragma unroll
            for (int j = 0; j < 2; ++j) {
                f32x4 z = {0.f, 0.f, 0.f, 0.f};
                acc[mt][j] = z;
            }
        for (int s = 0; s < 8; ++s) {
            f16x8 A0 = *(const f16x8*)&simF[(((s * 2 + 0) * 64 + laneS)) * 8];
            f16x8 A1 = *(const f16x8*)&simF[(((s * 2 + 1) * 64 + laneS)) * 8];
            #pragma unroll
            for (int j = 0; j < 2; ++j) {
                f16x8 B = *(const f16x8*)&Wf2P[((s * 8 + 2 * w + j) * 64 + lane) * 8];
                acc[0][j] = __builtin_amdgcn_mfma_f32_16x16x32_f16(A0, B, acc[0][j], 0, 0, 0);
                acc[1][j] = __builtin_amdgcn_mfma_f32_16x16x32_f16(A1, B, acc[1][j], 0, 0, 0);
            }
        }
        #pragma unroll
        for (int j = 0; j < 2; ++j) {
            int col = (2 * w + j) * 16 + (lane & 15);
            float bias = bf2v[col];
            #pragma unroll
            for (int mt = 0; mt < 2; ++mt) {
                #pragma unroll
                for (int r = 0; r < 4; ++r) {
                    int e = mt * 16 + ((lane >> 4) << 2) + r;
                    long eg = e0 + e;
                    if (eg < n_edges) out[eg * 128 + col] = acc[mt][j][r] + bias;
                }
            }
        }
    }
}

// ---------------- Fallback (small ws): f16 VALU node + edge kernels -----------
__global__ void node_kernel_fb(const float* __restrict__ x,
                               const float* __restrict__ Wc0, const float* __restrict__ bc0,
                               const float* __restrict__ Wc1, const float* __restrict__ Wc2,
                               const float* __restrict__ Wn0, const float* __restrict__ bn0,
                               const float* __restrict__ Wn1, const float* __restrict__ Wn2,
                               __half* __restrict__ Cp, __half* __restrict__ Np,
                               int n_nodes)
{
    int t = blockIdx.x * blockDim.x + threadIdx.x;
    if (t >= n_nodes * NFEAT) return;
    node_compute(x, Wc0, bc0, Wc1, Wc2, Wn0, bn0, Wn1, Wn2, Cp, Np, t);
}

#define EW 6
#define WPB 4
#define EB (EW * WPB)
#define BUFW 260
#define LATW 132

__global__ __launch_bounds__(256, 4) void edge_kernel_f16(
    const void* __restrict__ Cp, const void* __restrict__ Np,
    const int* __restrict__ eidx, const float* __restrict__ wig,
    const float* __restrict__ Ws0, const float* __restrict__ bs0,
    const float* __restrict__ Ws1, const float* __restrict__ bs1,
    const float* __restrict__ Ws2, const float* __restrict__ bs2,
    const float* __restrict__ Wf1, const float* __restrict__ bf1,
    const float* __restrict__ Wf2, const float* __restrict__ bf2v,
    float* __restrict__ out, int n_edges)
{
    __shared__ __align__(16) float bufS[WPB][EW][BUFW];
    __shared__ __align__(16) float latS[WPB][EW][LATW];

    const int w = threadIdx.x >> 6;
    const int lane = threadIdx.x & 63;
    const long e0 = (long)blockIdx.x * EB + (long)w * EW;

    const __half* Chrow[EW];
    const __half* Nhrow[EW];
    bool act[EW];
    #pragma unroll
    for (int e = 0; e < EW; ++e) {
        long eg = e0 + e;
        act[e] = eg < n_edges;
        long i0 = 0, i1 = 0;
        if (act[e]) { i0 = eidx[eg]; i1 = eidx[(long)n_edges + eg]; }
        Chrow[e] = (const __half*)Cp + i0 * NFEAT;
        Nhrow[e] = (const __half*)Np + i1 * NFEAT;
    }
    #define LDC(e, i) (__half2float(Chrow[e][i]))
    #define LDN(e, i) (__half2float(Nhrow[e][i]))

    #pragma unroll
    for (int e = 0; e < EW; ++e) {
        if (act[e]) {
            float c = LDC(e, lane);
            float n = LDN(e, lane);
            bufS[w][e][lane] = c * n;
        }
    }
    #pragma unroll
    for (int it = 0; it < 3; ++it) {
        int t = it * 64 + lane;
        int e = t >> 5;
        int m = t & 31;
        if (act[e]) {
            long eg = e0 + e;
            const float* wg = wig + eg * 81;
            int base = 64 + m * 3;
            float c0 = LDC(e, base + 0), c1 = LDC(e, base + 1), c2 = LDC(e, base + 2);
            float n0 = LDN(e, base + 0), n1 = LDN(e, base + 1), n2 = LDN(e, base + 2);
            #pragma unroll
            for (int q = 0; q < 3; ++q) {
                float r0 = wg[(1 + 0) * 9 + (1 + q)];
                float r1 = wg[(1 + 1) * 9 + (1 + q)];
                float r2 = wg[(1 + 2) * 9 + (1 + q)];
                float cq = c0 * r0 + c1 * r1 + c2 * r2;
                float nq = n0 * r0 + n1 * r1 + n2 * r2;
                bufS[w][e][base + q] = cq * nq;
            }
        }
    }
    #pragma unroll
    for (int it = 0; it < 2; ++it) {
        int t = it * 64 + lane;
        if (t < 96) {
            int e = t >> 4;
            int m = t & 15;
            if (act[e]) {
                long eg = e0 + e;
                const float* wg = wig + eg * 81;
                int base = 160 + m * 5;
                float c[5], n[5];
                #pragma unroll
                for (int d = 0; d < 5; ++d) { c[d] = LDC(e, base + d); n[d] = LDN(e, base + d); }
                #pragma unroll
                for (int q = 0; q < 5; ++q) {
                    float cq = 0.f, nq = 0.f;
                    #pragma unroll
                    for (int d = 0; d < 5; ++d) {
                        float rv = wg[(4 + d) * 9 + (4 + q)];
                        cq = fmaf(c[d], rv, cq);
                        nq = fmaf(n[d], rv, nq);
                    }
                    bufS[w][e][base + q] = cq * nq;
                }
            }
        }
    }
    __builtin_amdgcn_wave_barrier();

    const int k0 = lane * 4;
    float4 hacc[EW];
    {
        float4 hb = *(const float4*)&bf1[k0];
        #pragma unroll
        for (int e = 0; e < EW; ++e) hacc[e] = hb;
    }
    {
        const float* Wsl[3] = { Ws0, Ws1, Ws2 };
        const float* bsl[3] = { bs0, bs1, bs2 };
        const int Kl[3] = { 64, 96, 80 };
        const int offl[3] = { 0, 64, 160 };
        #pragma unroll
        for (int l = 0; l < 3; ++l) {
            const float* W = Wsl[l];
            const int K = Kl[l];
            const int off = offl[l];
            const int c0 = lane * 2;
            float acc0[EW], acc1[EW];
            {
                float b0v = bsl[l][c0];
                float b1v = bsl[l][c0 + 1];
                #pragma unroll
                for (int e = 0; e < EW; ++e) { acc0[e] = b0v; acc1[e] = b1v; }
            }
            for (int i0 = 0; i0 < K; i0 += 4) {
                float2 w0 = *(const float2*)&W[(i0 + 0) * 128 + c0];
                float2 w1 = *(const float2*)&W[(i0 + 1) * 128 + c0];
                float2 w2 = *(const float2*)&W[(i0 + 2) * 128 + c0];
                float2 w3 = *(const float2*)&W[(i0 + 3) * 128 + c0];
                #pragma unroll
                for (int e = 0; e < EW; ++e) {
                    float4 sv = *(const float4*)&bufS[w][e][off + i0];
                    acc0[e] = fmaf(sv.x, w0.x, acc0[e]);
                    acc0[e] = fmaf(sv.y, w1.x, acc0[e]);
                    acc0[e] = fmaf(sv.z, w2.x, acc0[e]);
                    acc0[e] = fmaf(sv.w, w3.x, acc0[e]);
                    acc1[e] = fmaf(sv.x, w0.y, acc1[e]);
                    acc1[e] = fmaf(sv.y, w1.y, acc1[e]);
                    acc1[e] = fmaf(sv.z, w2.y, acc1[e]);
                    acc1[e] = fmaf(sv.w, w3.y, acc1[e]);
                }
            }
            #pragma unroll
            for (int e = 0; e < EW; ++e) {
                float2 lv;
                lv.x = silu_f(acc0[e]);
                lv.y = silu_f(acc1[e]);
                *(float2*)&latS[w][e][c0] = lv;
            }
            __builtin_amdgcn_wave_barrier();

            const float* W1 = Wf1 + (size_t)l * 128 * 256;
            for (int i0 = 0; i0 < 128; i0 += 4) {
                float4 w0 = *(const float4*)&W1[(size_t)(i0 + 0) * 256 + k0];
                float4 w1 = *(const float4*)&W1[(size_t)(i0 + 1) * 256 + k0];
                float4 w2 = *(const float4*)&W1[(size_t)(i0 + 2) * 256 + k0];
                float4 w3 = *(const float4*)&W1[(size_t)(i0 + 3) * 256 + k0];
                #pragma unroll
                for (int e = 0; e < EW; ++e) {
                    float4 lv = *(const float4*)&latS[w][e][i0];
                    hacc[e].x = fmaf(lv.x, w0.x, hacc[e].x); hacc[e].x = fmaf(lv.y, w1.x, hacc[e].x);
                    hacc[e].x = fmaf(lv.z, w2.x, hacc[e].x); hacc[e].x = fmaf(lv.w, w3.x, hacc[e].x);
                    hacc[e].y = fmaf(lv.x, w0.y, hacc[e].y); hacc[e].y = fmaf(lv.y, w1.y, hacc[e].y);
                    hacc[e].y = fmaf(lv.z, w2.y, hacc[e].y); hacc[e].y = fmaf(lv.w, w3.y, hacc[e].y);
                    hacc[e].z = fmaf(lv.x, w0.z, hacc[e].z); hacc[e].z = fmaf(lv.y, w1.z, hacc[e].z);
                    hacc[e].z = fmaf(lv.z, w2.z, hacc[e].z); hacc[e].z = fmaf(lv.w, w3.z, hacc[e].z);
                    hacc[e].w = fmaf(lv.x, w0.w, hacc[e].w); hacc[e].w = fmaf(lv.y, w1.w, hacc[e].w);
                    hacc[e].w = fmaf(lv.z, w2.w, hacc[e].w); hacc[e].w = fmaf(lv.w, w3.w, hacc[e].w);
                }
            }
            __builtin_amdgcn_wave_barrier();
        }
    }
    #pragma unroll
    for (int e = 0; e < EW; ++e) {
        float4 hv;
        hv.x = silu_f(hacc[e].x); hv.y = silu_f(hacc[e].y);
        hv.z = silu_f(hacc[e].z); hv.w = silu_f(hacc[e].w);
        *(float4*)&bufS[w][e][k0] = hv;
    }
    __builtin_amdgcn_wave_barrier();
    {
        int c0 = lane * 2;
        float2 acc[EW];
        float2 bias = *(const float2*)&bf2v[c0];
        #pragma unroll
        for (int e = 0; e < EW; ++e) acc[e] = bias;
        for (int i0 = 0; i0 < 256; i0 += 4) {
            float2 w0 = *(const float2*)&Wf2[(size_t)(i0 + 0) * 128 + c0];
            float2 w1 = *(const float2*)&Wf2[(size_t)(i0 + 1) * 128 + c0];
            float2 w2 = *(const float2*)&Wf2[(size_t)(i0 + 2) * 128 + c0];
            float2 w3 = *(const float2*)&Wf2[(size_t)(i0 + 3) * 128 + c0];
            #pragma unroll
            for (int e = 0; e < EW; ++e) {
                float4 hv = *(const float4*)&bufS[w][e][i0];
                acc[e].x = fmaf(hv.x, w0.x, acc[e].x); acc[e].x = fmaf(hv.y, w1.x, acc[e].x);
                acc[e].x = fmaf(hv.z, w2.x, acc[e].x); acc[e].x = fmaf(hv.w, w3.x, acc[e].x);
                acc[e].y = fmaf(hv.x, w0.y, acc[e].y); acc[e].y = fmaf(hv.y, w1.y, acc[e].y);
                acc[e].y = fmaf(hv.z, w2.y, acc[e].y); acc[e].y = fmaf(hv.w, w3.y, acc[e].y);
            }
        }
        #pragma unroll
        for (int e = 0; e < EW; ++e) {
            long eg = e0 + e;
            if (eg < n_edges) {
                out[eg * 128 + c0 + 0] = acc[e].x;
                out[eg * 128 + c0 + 1] = acc[e].y;
            }
        }
    }
    #undef LDC
    #undef LDN
}

extern "C" void kernel_launch(void* const* d_in, const int* in_sizes, int n_in,
                              void* d_out, int out_size, void* d_ws, size_t ws_size,
                              hipStream_t stream) {
    const float* x    = (const float*)d_in[0];
    // d_in[1] = active_edge_vector: unused by the reference
    const int* eidx   = (const int*)d_in[2];
    const float* wig  = (const float*)d_in[3];
    const float* Wc0  = (const float*)d_in[4];
    const float* bc0  = (const float*)d_in[5];
    const float* Wc1  = (const float*)d_in[6];
    const float* Wc2  = (const float*)d_in[7];
    const float* Wn0  = (const float*)d_in[8];
    const float* bn0  = (const float*)d_in[9];
    const float* Wn1  = (const float*)d_in[10];
    const float* Wn2  = (const float*)d_in[11];
    const float* Ws0  = (const float*)d_in[12];
    const float* bs0  = (const float*)d_in[13];
    const float* Ws1  = (const float*)d_in[14];
    const float* bs1  = (const float*)d_in[15];
    const float* Ws2  = (const float*)d_in[16];
    const float* bs2  = (const float*)d_in[17];
    const float* Wf1  = (const float*)d_in[18];
    const float* bf1  = (const float*)d_in[19];
    const float* Wf2  = (const float*)d_in[20];
    const float* bf2v = (const float*)d_in[21];
    float* out = (float*)d_out;

    const int n_nodes = in_sizes[0] / NFEAT;
    const int n_edges = in_sizes[2] / 2;
    const size_t cn = (size_t)n_nodes * NFEAT;

    const int grdA = (int)((cn + 255) / 256);
    const size_t needM = cn * 2 * sizeof(__half) + (size_t)163840 * sizeof(f16);

    if (ws_size >= needM) {
        __half* C  = (__half*)d_ws;
        __half* Nh = C + cn;
        f16* P = (f16*)((char*)d_ws + cn * 2 * sizeof(__half));
        prep_kernel<<<grdA + 640, 256, 0, stream>>>(x, Wc0, bc0, Wc1, Wc2,
                                                    Wn0, bn0, Wn1, Wn2,
                                                    Ws0, Ws1, Ws2, Wf1, Wf2,
                                                    C, Nh, P, n_nodes, grdA);
        const int grdM = (n_edges + 31) / 32;
        edge_mfma<<<grdM, 256, 0, stream>>>((const f16*)C, (const f16*)Nh,
                                            eidx, wig, P,
                                            bs0, bs1, bs2, bf1, bf2v,
                                            out, n_edges);
    } else {
        __half* C  = (__half*)d_ws;
        __half* Nh = C + cn;
        node_kernel_fb<<<grdA, 256, 0, stream>>>(x, Wc0, bc0, Wc1, Wc2,
                                                 Wn0, bn0, Wn1, Wn2,
                                                 C, Nh, n_nodes);
        const int grdB = (n_edges + EB - 1) / EB;
        edge_kernel_f16<<<grdB, 256, 0, stream>>>((const void*)C, (const void*)Nh,
                                                  eidx, wig,
                                                  Ws0, bs0, Ws1, bs1, Ws2, bs2,
                                                  Wf1, bf1, Wf2, bf2v,
                                                  out, n_edges);
    }
}